// Round 6
// baseline (521.731 us; speedup 1.0000x reference)
//
#include <hip/hip_runtime.h>
#include <hip/hip_bf16.h>

// TemporalAttentionWithDecay, MI355X gfx950.  B=4,N=1024,T=32,C=256,H=8,d=32.
// R5 (resubmit; prior round was an infra failure): ILP attack. h A-fragments
// hoisted to 64 VGPRs ONCE (all projection passes share them) -> passes are
// pure {B-load stream + MFMA}. B-streams pipelined 3 quarters deep across
// pass-pairs (G,V) and (K,Q). __launch_bounds__(256,2) gives the 256-VGPR
// budget this needs.

typedef __attribute__((ext_vector_type(8))) short  s16x8;   // 8 bf16
typedef __attribute__((ext_vector_type(4))) float  f32x4;   // MFMA acc
typedef __attribute__((ext_vector_type(4))) unsigned short us16x4;

#define MFMA16(a, b, c) __builtin_amdgcn_mfma_f32_16x16x32_bf16((a), (b), (c), 0, 0, 0)

static __device__ __forceinline__ unsigned short f2bfu(float f) {
  __hip_bfloat16 h = __float2bfloat16(f);          // RNE
  return __builtin_bit_cast(unsigned short, h);
}
static __device__ __forceinline__ unsigned pack2(float lo, float hi) {
  return (unsigned)f2bfu(lo) | ((unsigned)f2bfu(hi) << 16);
}
static __device__ __forceinline__ float bf_lo(unsigned u) {
  union { unsigned u; float f; } v; v.u = u << 16; return v.f;
}
static __device__ __forceinline__ float bf_hi(unsigned u) {
  union { unsigned u; float f; } v; v.u = u & 0xFFFF0000u; return v.f;
}

// ---- LDS layout (bytes)
#define RS      528     // region A row stride: 256 bf16 + 16B pad (conflict-free b128)
#define ZSTR    72      // zone row stride: 32 bf16 + 8B pad (conflict-free b128)
#define LDS_A   0       // h (phases 0/1), then g*o (phase 3): 32*528 = 16896
#define LDS_TS  16896   // timestamps f32[32]
#define LDS_Z   17024   // 4 per-wave zones
#define ZONE    4608    // ZA (k/q/P stripe, 2304) + ZB (vT, 2304)
#define LDS_TOTAL (LDS_Z + 4 * ZONE)   // 35456

// ---- ws layout: 5 weights in B-fragment-linear bf16, then exp(log_lambda).
// Fragment (ntg, ks, lane, i) holds W[j=16*ntg+(lane&15)][c=32*ks+8*(lane>>4)+i].
#define WS_WQ   0
#define WS_WK   131072
#define WS_WV   262144
#define WS_WG   393216
#define WS_WO   524288
#define WS_LAM  655360

__global__ void prep_kernel(const float* __restrict__ Wq, const float* __restrict__ Wk,
                            const float* __restrict__ Wv, const float* __restrict__ Wg,
                            const float* __restrict__ Wo, const float* __restrict__ ll,
                            char* __restrict__ ws) {
  int tid = blockIdx.x * 256 + threadIdx.x;
  if (tid < 5 * 8192) {
    int m      = tid >> 13;
    int within = tid & 8191;
    int lane   = within & 63;
    int j = 16 * (within >> 9) + (lane & 15);
    int c = 32 * ((within >> 6) & 7) + 8 * (lane >> 4);
    const float* W = (m == 0) ? Wq : (m == 1) ? Wk : (m == 2) ? Wv : (m == 3) ? Wg : Wo;
    const float* src = W + j * 256 + c;
    s16x8 o;
#pragma unroll
    for (int i = 0; i < 8; ++i) o[i] = (short)f2bfu(src[i]);
    *(s16x8*)(ws + (size_t)tid * 16) = o;
  } else if (tid < 5 * 8192 + 8) {
    ((float*)(ws + WS_LAM))[tid - 40960] = __expf(ll[tid - 40960]);
  }
}

// Wo pass (phase 3 only): streams A from LDS, prefetches its B-frags.
template <int NT>
static __device__ __forceinline__ void gemmNT(const char* lds, const char* wmat,
                                              int ntg0, int lane, f32x4 acc[2][NT]) {
  const int l15 = lane & 15, l4 = lane >> 4;
  const s16x8* Bf = (const s16x8*)wmat + ntg0 * 8 * 64 + lane;
  s16x8 b[NT][8];
#pragma unroll
  for (int nt = 0; nt < NT; ++nt)
#pragma unroll
    for (int ks = 0; ks < 8; ++ks) b[nt][ks] = Bf[(nt * 8 + ks) * 64];
#pragma unroll
  for (int mt = 0; mt < 2; ++mt)
#pragma unroll
    for (int nt = 0; nt < NT; ++nt) acc[mt][nt] = (f32x4){0.f, 0.f, 0.f, 0.f};
#pragma unroll
  for (int ks = 0; ks < 8; ++ks) {
    s16x8 a[2];
#pragma unroll
    for (int mt = 0; mt < 2; ++mt)
      a[mt] = *(const s16x8*)(lds + LDS_A + (16 * mt + l15) * RS + 64 * ks + 16 * l4);
#pragma unroll
    for (int nt = 0; nt < NT; ++nt)
#pragma unroll
      for (int mt = 0; mt < 2; ++mt) acc[mt][nt] = MFMA16(a[mt], b[nt][ks], acc[mt][nt]);
  }
}

// 8 MFMAs of one quarter (one matrix, one nt column-tile) on hoisted A.
static __device__ __forceinline__ void quarter(const s16x8 ah[2][8], const s16x8 b[8],
                                               f32x4 acc[2][2], int nt) {
#pragma unroll
  for (int ks = 0; ks < 8; ++ks)
#pragma unroll
    for (int mt = 0; mt < 2; ++mt)
      acc[mt][nt] = MFMA16(ah[mt][ks], b[ks], acc[mt][nt]);
}

__global__ __launch_bounds__(256, 2) void fused_kernel(
    const float* __restrict__ x, const float* __restrict__ tsg,
    const float* __restrict__ gamma, const float* __restrict__ beta,
    const float* __restrict__ bq, const char* __restrict__ ws,
    float* __restrict__ out) {
  extern __shared__ __align__(16) char lds[];
  const int tid = threadIdx.x;
  const int lane = tid & 63;
  const int w = tid >> 6;               // wave 0..3; handles heads {2w, 2w+1}
  const int l15 = lane & 15, l4 = lane >> 4;
  const int blk = blockIdx.x;           // one bn-seq: rows [blk*32, blk*32+32)
  char* zA = lds + LDS_Z + w * ZONE;    // wave-private: k/q/P stripes
  char* zB = zA + 2304;                 // wave-private: vT

  // ---------------- Phase 0: x -> LayerNorm -> h (bf16, region A) ----------------
  {
    const int r = tid >> 3, sub = tid & 7;   // 32 rows x 8 threads
    const float* xr = x + ((size_t)blk * 32 + r) * 256 + sub * 32;
    float4 xv[8];
    float s = 0.f, s2 = 0.f;
#pragma unroll
    for (int u = 0; u < 8; ++u) {
      xv[u] = *(const float4*)(xr + 4 * u);
      s  += xv[u].x + xv[u].y + xv[u].z + xv[u].w;
      s2 += xv[u].x * xv[u].x + xv[u].y * xv[u].y + xv[u].z * xv[u].z + xv[u].w * xv[u].w;
    }
#pragma unroll
    for (int m = 1; m <= 4; m <<= 1) { s += __shfl_xor(s, m); s2 += __shfl_xor(s2, m); }
    float mu = s * (1.f / 256.f);
    float rstd = rsqrtf(s2 * (1.f / 256.f) - mu * mu + 1e-5f);
#pragma unroll
    for (int u = 0; u < 8; ++u) {
      int c = sub * 32 + 4 * u;
      float4 gv = *(const float4*)(gamma + c);
      float4 bv = *(const float4*)(beta + c);
      us16x4 hb;
      hb[0] = f2bfu((xv[u].x - mu) * rstd * gv.x + bv.x);
      hb[1] = f2bfu((xv[u].y - mu) * rstd * gv.y + bv.y);
      hb[2] = f2bfu((xv[u].z - mu) * rstd * gv.z + bv.z);
      hb[3] = f2bfu((xv[u].w - mu) * rstd * gv.w + bv.w);
      *(us16x4*)(lds + LDS_A + r * RS + 2 * c) = hb;
    }
    if (tid < 32) ((float*)(lds + LDS_TS))[tid] = tsg[(blk >> 10) * 32 + tid];
  }
  __syncthreads();

  // ---- Hoist all 16 h A-fragments into registers (shared by all passes) ----
  s16x8 ah[2][8];
#pragma unroll
  for (int mt = 0; mt < 2; ++mt)
#pragma unroll
    for (int ks = 0; ks < 8; ++ks)
      ah[mt][ks] = *(const s16x8*)(lds + LDS_A + (16 * mt + l15) * RS + 64 * ks + 16 * l4);

  // ---------------- Phase 1+2: per-head projections + attention ----------------
  const float* tsl = (const float*)(lds + LDS_TS);
  const float* lam = (const float*)(ws + WS_LAM);
  const float tc0 = tsl[l15], tc1 = tsl[l15 + 16];
  float trow[8];
#pragma unroll
  for (int mh = 0; mh < 2; ++mh)
#pragma unroll
    for (int r = 0; r < 4; ++r) trow[mh * 4 + r] = tsl[16 * mh + 4 * l4 + r];
  const f32x4 zf = {0.f, 0.f, 0.f, 0.f};
  unsigned gopk[2][2][2][2];   // g*o bf16-packed, persists across head loop

#pragma unroll
  for (int hp = 0; hp < 2; ++hp) {
    const int h = 2 * w + hp;
    const s16x8* BG = (const s16x8*)(ws + WS_WG) + lane;
    const s16x8* BV = (const s16x8*)(ws + WS_WV) + lane;
    const s16x8* BK = (const s16x8*)(ws + WS_WK) + lane;
    const s16x8* BQ = (const s16x8*)(ws + WS_WQ) + lane;
    unsigned gpk[2][2][2];

    // ===== pass-pair (G, V): 4 quarters, 3-deep B prefetch =====
    f32x4 accG[2][2], accV[2][2];
    {
      s16x8 bX0[8], bY0[8], bX1[8], bY1[8];
#pragma unroll
      for (int ks = 0; ks < 8; ++ks) bX0[ks] = BG[((2 * h + 0) * 8 + ks) * 64];
#pragma unroll
      for (int ks = 0; ks < 8; ++ks) bY0[ks] = BV[((2 * h + 0) * 8 + ks) * 64];
#pragma unroll
      for (int ks = 0; ks < 8; ++ks) bX1[ks] = BG[((2 * h + 1) * 8 + ks) * 64];
#pragma unroll
      for (int mt = 0; mt < 2; ++mt)
#pragma unroll
        for (int nt = 0; nt < 2; ++nt) { accG[mt][nt] = zf; accV[mt][nt] = zf; }
      quarter(ah, bX0, accG, 0);
#pragma unroll
      for (int ks = 0; ks < 8; ++ks) bY1[ks] = BV[((2 * h + 1) * 8 + ks) * 64];
      quarter(ah, bY0, accV, 0);
      quarter(ah, bX1, accG, 1);
      quarter(ah, bY1, accV, 1);
    }
    // G epilogue: sigmoid, pack
#pragma unroll
    for (int mt = 0; mt < 2; ++mt)
#pragma unroll
      for (int nt = 0; nt < 2; ++nt)
#pragma unroll
        for (int rp = 0; rp < 2; ++rp)
          gpk[mt][nt][rp] = pack2(1.f / (1.f + __expf(-accG[mt][nt][2 * rp])),
                                  1.f / (1.f + __expf(-accG[mt][nt][2 * rp + 1])));
    // V epilogue: vT -> zone B ([d][s], dword pairs along s)
#pragma unroll
    for (int mt = 0; mt < 2; ++mt)
#pragma unroll
      for (int nt = 0; nt < 2; ++nt)
#pragma unroll
        for (int rp = 0; rp < 2; ++rp)
          *(unsigned*)(zB + (16 * nt + l15) * ZSTR + 2 * (16 * mt + 4 * l4 + 2 * rp)) =
              pack2(accV[mt][nt][2 * rp], accV[mt][nt][2 * rp + 1]);

    // ===== pass-pair (K, Q): 4 quarters, 3-deep B prefetch =====
    f32x4 accK[2][2], accQ[2][2];
    {
      s16x8 bX0[8], bY0[8], bX1[8], bY1[8];
#pragma unroll
      for (int ks = 0; ks < 8; ++ks) bX0[ks] = BK[((2 * h + 0) * 8 + ks) * 64];
#pragma unroll
      for (int ks = 0; ks < 8; ++ks) bY0[ks] = BQ[((2 * h + 0) * 8 + ks) * 64];
#pragma unroll
      for (int ks = 0; ks < 8; ++ks) bX1[ks] = BK[((2 * h + 1) * 8 + ks) * 64];
#pragma unroll
      for (int mt = 0; mt < 2; ++mt)
#pragma unroll
        for (int nt = 0; nt < 2; ++nt) { accK[mt][nt] = zf; accQ[mt][nt] = zf; }
      quarter(ah, bX0, accK, 0);
#pragma unroll
      for (int ks = 0; ks < 8; ++ks) bY1[ks] = BQ[((2 * h + 1) * 8 + ks) * 64];
      quarter(ah, bY0, accQ, 0);
      quarter(ah, bX1, accK, 1);
      quarter(ah, bY1, accQ, 1);
    }
    // K epilogue: stripe zone A -> B-frags in regs
#pragma unroll
    for (int mt = 0; mt < 2; ++mt)
#pragma unroll
      for (int nt = 0; nt < 2; ++nt)
#pragma unroll
        for (int r = 0; r < 4; ++r)
          *(short*)(zA + (16 * mt + 4 * l4 + r) * ZSTR + 2 * (16 * nt + l15)) =
              (short)f2bfu(accK[mt][nt][r]);
    s16x8 bk0 = *(const s16x8*)(zA + l15 * ZSTR + 16 * l4);          // wave-private,
    s16x8 bk1 = *(const s16x8*)(zA + (16 + l15) * ZSTR + 16 * l4);   // in-order LDS pipe
    // Q epilogue: +bias, *1/sqrt(d) -> stripe zone A (k stripe dead)
    {
      float bq0 = bq[32 * h + l15], bq1 = bq[32 * h + 16 + l15];
#pragma unroll
      for (int mt = 0; mt < 2; ++mt)
#pragma unroll
        for (int nt = 0; nt < 2; ++nt)
#pragma unroll
          for (int r = 0; r < 4; ++r)
            *(short*)(zA + (16 * mt + 4 * l4 + r) * ZSTR + 2 * (16 * nt + l15)) =
                (short)f2bfu((accQ[mt][nt][r] + (nt ? bq1 : bq0)) * 0.17677669529663687f);
    }
    s16x8 aq0 = *(const s16x8*)(zA + l15 * ZSTR + 16 * l4);
    s16x8 aq1 = *(const s16x8*)(zA + (16 + l15) * ZSTR + 16 * l4);

    // --- QK^T
    f32x4 sc[2][2];
    sc[0][0] = MFMA16(aq0, bk0, zf);
    sc[0][1] = MFMA16(aq0, bk1, zf);
    sc[1][0] = MFMA16(aq1, bk0, zf);
    sc[1][1] = MFMA16(aq1, bk1, zf);

    // --- bias + softmax (rows in regs, 16-lane shuffle reduce), P -> zone A
    const float lamh = lam[h];
#pragma unroll
    for (int mh = 0; mh < 2; ++mh)
#pragma unroll
      for (int r = 0; r < 4; ++r) {
        float tr = trow[mh * 4 + r];
        float a0 = sc[mh][0][r] - lamh * fabsf(tr - tc0);
        float a1 = sc[mh][1][r] - lamh * fabsf(tr - tc1);
        float m = fmaxf(a0, a1);
        m = fmaxf(m, __shfl_xor(m, 1)); m = fmaxf(m, __shfl_xor(m, 2));
        m = fmaxf(m, __shfl_xor(m, 4)); m = fmaxf(m, __shfl_xor(m, 8));
        float e0 = __expf(a0 - m), e1 = __expf(a1 - m);
        float su = e0 + e1;
        su += __shfl_xor(su, 1); su += __shfl_xor(su, 2);
        su += __shfl_xor(su, 4); su += __shfl_xor(su, 8);
        float inv = 1.0f / su;
        int t = 16 * mh + 4 * l4 + r;
        *(short*)(zA + t * ZSTR + 2 * l15)        = (short)f2bfu(e0 * inv);
        *(short*)(zA + t * ZSTR + 2 * (l15 + 16)) = (short)f2bfu(e1 * inv);
      }

    // --- PV + gate -> packed regs (region A still holds h; can't write yet)
    s16x8 ap0 = *(const s16x8*)(zA + l15 * ZSTR + 16 * l4);
    s16x8 ap1 = *(const s16x8*)(zA + (16 + l15) * ZSTR + 16 * l4);
    s16x8 bv0 = *(const s16x8*)(zB + l15 * ZSTR + 16 * l4);
    s16x8 bv1 = *(const s16x8*)(zB + (16 + l15) * ZSTR + 16 * l4);
#pragma unroll
    for (int mh = 0; mh < 2; ++mh)
#pragma unroll
      for (int nd = 0; nd < 2; ++nd) {
        f32x4 oa = MFMA16(mh ? ap1 : ap0, nd ? bv1 : bv0, zf);
#pragma unroll
        for (int rp = 0; rp < 2; ++rp) {
          unsigned gu = gpk[mh][nd][rp];
          gopk[hp][mh][nd][rp] =
              pack2(oa[2 * rp] * bf_lo(gu), oa[2 * rp + 1] * bf_hi(gu));
        }
      }
  }
  __syncthreads();   // all waves done reading h -> region A becomes g*o

  // ---------------- Phase 3a: publish g*o (bf16) to region A ----------------
#pragma unroll
  for (int hp = 0; hp < 2; ++hp)
#pragma unroll
    for (int mh = 0; mh < 2; ++mh)
#pragma unroll
      for (int nd = 0; nd < 2; ++nd)
#pragma unroll
        for (int rp = 0; rp < 2; ++rp) {
          unsigned gu = gopk[hp][mh][nd][rp];
          int j = 32 * (2 * w + hp) + 16 * nd + l15;
          int r0 = 16 * mh + 4 * l4 + 2 * rp;
          *(short*)(lds + LDS_A + r0 * RS + 2 * j)       = (short)(gu & 0xFFFFu);
          *(short*)(lds + LDS_A + (r0 + 1) * RS + 2 * j) = (short)(gu >> 16);
        }
  __syncthreads();

  // ---------------- Phase 3b: out = x + (g*o) @ Wo^T  (two halves) ----------------
#pragma unroll
  for (int half = 0; half < 2; ++half) {
    f32x4 facc[2][2];
    gemmNT<2>(lds, ws + WS_WO, 4 * w + 2 * half, lane, facc);
#pragma unroll
    for (int mt = 0; mt < 2; ++mt)
#pragma unroll
      for (int nt = 0; nt < 2; ++nt)
#pragma unroll
        for (int r = 0; r < 4; ++r) {
          int row = 16 * mt + 4 * l4 + r;
          int j = 64 * w + 32 * half + 16 * nt + l15;
          size_t gi = ((size_t)blk * 32 + row) * 256 + j;
          out[gi] = facc[mt][nt][r] + x[gi];
        }
  }
}

extern "C" void kernel_launch(void* const* d_in, const int* in_sizes, int n_in,
                              void* d_out, int out_size, void* d_ws, size_t ws_size,
                              hipStream_t stream) {
  const float* x     = (const float*)d_in[0];
  const float* ts    = (const float*)d_in[1];
  const float* gamma = (const float*)d_in[3];
  const float* beta  = (const float*)d_in[4];
  const float* Wq    = (const float*)d_in[5];
  const float* bq    = (const float*)d_in[6];
  const float* Wk    = (const float*)d_in[7];
  const float* Wv    = (const float*)d_in[8];
  const float* Wg    = (const float*)d_in[9];
  const float* Wo    = (const float*)d_in[10];
  const float* ll    = (const float*)d_in[11];
  char* ws   = (char*)d_ws;
  float* out = (float*)d_out;

  prep_kernel<<<161, 256, 0, stream>>>(Wq, Wk, Wv, Wg, Wo, ll, ws);

  (void)hipFuncSetAttribute((const void*)fused_kernel,
                            hipFuncAttributeMaxDynamicSharedMemorySize, LDS_TOTAL);
  fused_kernel<<<4096, 256, LDS_TOTAL, stream>>>(x, ts, gamma, beta, bq, ws, out);
}

// Round 8
// 387.806 us; speedup vs baseline: 1.3453x; 1.3453x over previous
//
#include <hip/hip_runtime.h>
#include <hip/hip_bf16.h>

// TemporalAttentionWithDecay, MI355X gfx950.  B=4,N=1024,T=32,C=256,H=8,d=32.
// R7 (resubmit; prior round was an infra failure): R4 base + feasible reg plan:
//   - ah[2][8] (h A-frags) hoisted ONCE (64 VGPR) -> kills 128 ds_read_b128/wave
//   - per pass exactly one b[2][8] batch (64 VGPR) + sched_barrier(0) fence so
//     the scheduler can't de-batch the loads (one L2 latency window per pass)
//   - launch_bounds(256,2): ~256-reg budget, live set ~190. No pass-pairs.

typedef __attribute__((ext_vector_type(8))) short  s16x8;   // 8 bf16
typedef __attribute__((ext_vector_type(4))) float  f32x4;   // MFMA acc
typedef __attribute__((ext_vector_type(4))) unsigned short us16x4;

#define MFMA16(a, b, c) __builtin_amdgcn_mfma_f32_16x16x32_bf16((a), (b), (c), 0, 0, 0)

static __device__ __forceinline__ unsigned short f2bfu(float f) {
  __hip_bfloat16 h = __float2bfloat16(f);          // RNE
  return __builtin_bit_cast(unsigned short, h);
}
static __device__ __forceinline__ unsigned pack2(float lo, float hi) {
  return (unsigned)f2bfu(lo) | ((unsigned)f2bfu(hi) << 16);
}
static __device__ __forceinline__ float bf_lo(unsigned u) {
  union { unsigned u; float f; } v; v.u = u << 16; return v.f;
}
static __device__ __forceinline__ float bf_hi(unsigned u) {
  union { unsigned u; float f; } v; v.u = u & 0xFFFF0000u; return v.f;
}

// ---- LDS layout (bytes)
#define RS      528     // region A row stride: 256 bf16 + 16B pad (conflict-free b128)
#define ZSTR    72      // zone row stride: 32 bf16 + 8B pad (conflict-free b128)
#define LDS_A   0       // h (phases 0/1), then g*o (phase 3): 32*528 = 16896
#define LDS_TS  16896   // timestamps f32[32]
#define LDS_Z   17024   // 4 per-wave zones
#define ZONE    4608    // ZA (k/q/P stripe, 2304) + ZB (vT, 2304)
#define LDS_TOTAL (LDS_Z + 4 * ZONE)   // 35456

// ---- ws layout: 5 weights in B-fragment-linear bf16, then exp(log_lambda).
// Fragment (ntg, ks, lane, i) holds W[j=16*ntg+(lane&15)][c=32*ks+8*(lane>>4)+i].
#define WS_WQ   0
#define WS_WK   131072
#define WS_WV   262144
#define WS_WG   393216
#define WS_WO   524288
#define WS_LAM  655360

__global__ void prep_kernel(const float* __restrict__ Wq, const float* __restrict__ Wk,
                            const float* __restrict__ Wv, const float* __restrict__ Wg,
                            const float* __restrict__ Wo, const float* __restrict__ ll,
                            char* __restrict__ ws) {
  int tid = blockIdx.x * 256 + threadIdx.x;
  if (tid < 5 * 8192) {
    int m      = tid >> 13;
    int within = tid & 8191;
    int lane   = within & 63;
    int j = 16 * (within >> 9) + (lane & 15);
    int c = 32 * ((within >> 6) & 7) + 8 * (lane >> 4);
    const float* W = (m == 0) ? Wq : (m == 1) ? Wk : (m == 2) ? Wv : (m == 3) ? Wg : Wo;
    const float* src = W + j * 256 + c;
    s16x8 o;
#pragma unroll
    for (int i = 0; i < 8; ++i) o[i] = (short)f2bfu(src[i]);
    *(s16x8*)(ws + (size_t)tid * 16) = o;
  } else if (tid < 5 * 8192 + 8) {
    ((float*)(ws + WS_LAM))[tid - 40960] = __expf(ll[tid - 40960]);
  }
}

// Projection pass on hoisted A: one batched B-load (16 frags), fence, 32 MFMAs.
static __device__ __forceinline__ void passB2(const s16x8 ah[2][8], const char* wmat,
                                              int ntg0, int lane, f32x4 acc[2][2]) {
  const s16x8* Bf = (const s16x8*)wmat + ntg0 * 8 * 64 + lane;
  s16x8 b[2][8];
#pragma unroll
  for (int nt = 0; nt < 2; ++nt)
#pragma unroll
    for (int ks = 0; ks < 8; ++ks) b[nt][ks] = Bf[(nt * 8 + ks) * 64];
  __builtin_amdgcn_sched_barrier(0);   // keep the 16 loads batched (1 vmcnt window)
#pragma unroll
  for (int mt = 0; mt < 2; ++mt)
#pragma unroll
    for (int nt = 0; nt < 2; ++nt) acc[mt][nt] = (f32x4){0.f, 0.f, 0.f, 0.f};
#pragma unroll
  for (int ks = 0; ks < 8; ++ks)
#pragma unroll
    for (int nt = 0; nt < 2; ++nt)
#pragma unroll
      for (int mt = 0; mt < 2; ++mt)
        acc[mt][nt] = MFMA16(ah[mt][ks], b[nt][ks], acc[mt][nt]);
}

// Wo pass (A = g*o from LDS; B prefetched like R4).
template <int NT>
static __device__ __forceinline__ void gemmNT(const char* lds, const char* wmat,
                                              int ntg0, int lane, f32x4 acc[2][NT]) {
  const int l15 = lane & 15, l4 = lane >> 4;
  const s16x8* Bf = (const s16x8*)wmat + ntg0 * 8 * 64 + lane;
  s16x8 b[NT][8];
#pragma unroll
  for (int nt = 0; nt < NT; ++nt)
#pragma unroll
    for (int ks = 0; ks < 8; ++ks) b[nt][ks] = Bf[(nt * 8 + ks) * 64];
  __builtin_amdgcn_sched_barrier(0);
#pragma unroll
  for (int mt = 0; mt < 2; ++mt)
#pragma unroll
    for (int nt = 0; nt < NT; ++nt) acc[mt][nt] = (f32x4){0.f, 0.f, 0.f, 0.f};
#pragma unroll
  for (int ks = 0; ks < 8; ++ks) {
    s16x8 a[2];
#pragma unroll
    for (int mt = 0; mt < 2; ++mt)
      a[mt] = *(const s16x8*)(lds + LDS_A + (16 * mt + l15) * RS + 64 * ks + 16 * l4);
#pragma unroll
    for (int nt = 0; nt < NT; ++nt)
#pragma unroll
      for (int mt = 0; mt < 2; ++mt) acc[mt][nt] = MFMA16(a[mt], b[nt][ks], acc[mt][nt]);
  }
}

__global__ __launch_bounds__(256, 2) void fused_kernel(
    const float* __restrict__ x, const float* __restrict__ tsg,
    const float* __restrict__ gamma, const float* __restrict__ beta,
    const float* __restrict__ bq, const char* __restrict__ ws,
    float* __restrict__ out) {
  extern __shared__ __align__(16) char lds[];
  const int tid = threadIdx.x;
  const int lane = tid & 63;
  const int w = tid >> 6;               // wave 0..3; handles heads {2w, 2w+1}
  const int l15 = lane & 15, l4 = lane >> 4;
  const int blk = blockIdx.x;           // one bn-seq: rows [blk*32, blk*32+32)
  char* zA = lds + LDS_Z + w * ZONE;    // wave-private: k/q/P stripes
  char* zB = zA + 2304;                 // wave-private: vT

  // ---------------- Phase 0: x -> LayerNorm -> h (bf16, region A) ----------------
  {
    const int r = tid >> 3, sub = tid & 7;   // 32 rows x 8 threads
    const float* xr = x + ((size_t)blk * 32 + r) * 256 + sub * 32;
    float4 xv[8];
    float s = 0.f, s2 = 0.f;
#pragma unroll
    for (int u = 0; u < 8; ++u) {
      xv[u] = *(const float4*)(xr + 4 * u);
      s  += xv[u].x + xv[u].y + xv[u].z + xv[u].w;
      s2 += xv[u].x * xv[u].x + xv[u].y * xv[u].y + xv[u].z * xv[u].z + xv[u].w * xv[u].w;
    }
#pragma unroll
    for (int m = 1; m <= 4; m <<= 1) { s += __shfl_xor(s, m); s2 += __shfl_xor(s2, m); }
    float mu = s * (1.f / 256.f);
    float rstd = rsqrtf(s2 * (1.f / 256.f) - mu * mu + 1e-5f);
#pragma unroll
    for (int u = 0; u < 8; ++u) {
      int c = sub * 32 + 4 * u;
      float4 gv = *(const float4*)(gamma + c);
      float4 bv = *(const float4*)(beta + c);
      us16x4 hb;
      hb[0] = f2bfu((xv[u].x - mu) * rstd * gv.x + bv.x);
      hb[1] = f2bfu((xv[u].y - mu) * rstd * gv.y + bv.y);
      hb[2] = f2bfu((xv[u].z - mu) * rstd * gv.z + bv.z);
      hb[3] = f2bfu((xv[u].w - mu) * rstd * gv.w + bv.w);
      *(us16x4*)(lds + LDS_A + r * RS + 2 * c) = hb;
    }
    if (tid < 32) ((float*)(lds + LDS_TS))[tid] = tsg[(blk >> 10) * 32 + tid];
  }
  __syncthreads();

  // ---- Hoist all 16 h A-fragments into registers (shared by all 8 passes) ----
  s16x8 ah[2][8];
#pragma unroll
  for (int mt = 0; mt < 2; ++mt)
#pragma unroll
    for (int ks = 0; ks < 8; ++ks)
      ah[mt][ks] = *(const s16x8*)(lds + LDS_A + (16 * mt + l15) * RS + 64 * ks + 16 * l4);

  // ---------------- Phase 1+2: per-head projections + attention ----------------
  const float* tsl = (const float*)(lds + LDS_TS);
  const float* lam = (const float*)(ws + WS_LAM);
  const float tc0 = tsl[l15], tc1 = tsl[l15 + 16];
  float trow[8];
#pragma unroll
  for (int mh = 0; mh < 2; ++mh)
#pragma unroll
    for (int r = 0; r < 4; ++r) trow[mh * 4 + r] = tsl[16 * mh + 4 * l4 + r];
  const f32x4 zf = {0.f, 0.f, 0.f, 0.f};
  unsigned gopk[2][2][2][2];   // g*o bf16-packed, persists across head loop

#pragma unroll
  for (int hp = 0; hp < 2; ++hp) {
    const int h = 2 * w + hp;
    f32x4 acc[2][2];
    unsigned gpk[2][2][2];

    // --- G pass -> sigmoid, packed in regs
    passB2(ah, ws + WS_WG, 2 * h, lane, acc);
#pragma unroll
    for (int mt = 0; mt < 2; ++mt)
#pragma unroll
      for (int nt = 0; nt < 2; ++nt)
#pragma unroll
        for (int rp = 0; rp < 2; ++rp)
          gpk[mt][nt][rp] = pack2(1.f / (1.f + __expf(-acc[mt][nt][2 * rp])),
                                  1.f / (1.f + __expf(-acc[mt][nt][2 * rp + 1])));

    // --- V pass -> vT straight to zone B ([d][s], dword pairs along s)
    passB2(ah, ws + WS_WV, 2 * h, lane, acc);
#pragma unroll
    for (int mt = 0; mt < 2; ++mt)
#pragma unroll
      for (int nt = 0; nt < 2; ++nt)
#pragma unroll
        for (int rp = 0; rp < 2; ++rp)
          *(unsigned*)(zB + (16 * nt + l15) * ZSTR + 2 * (16 * mt + 4 * l4 + 2 * rp)) =
              pack2(acc[mt][nt][2 * rp], acc[mt][nt][2 * rp + 1]);

    // --- K pass -> stripe zone A -> B-frags in regs
    passB2(ah, ws + WS_WK, 2 * h, lane, acc);
#pragma unroll
    for (int mt = 0; mt < 2; ++mt)
#pragma unroll
      for (int nt = 0; nt < 2; ++nt)
#pragma unroll
        for (int r = 0; r < 4; ++r)
          *(short*)(zA + (16 * mt + 4 * l4 + r) * ZSTR + 2 * (16 * nt + l15)) =
              (short)f2bfu(acc[mt][nt][r]);
    s16x8 bk0 = *(const s16x8*)(zA + l15 * ZSTR + 16 * l4);          // wave-private,
    s16x8 bk1 = *(const s16x8*)(zA + (16 + l15) * ZSTR + 16 * l4);   // in-order LDS pipe

    // --- Q pass -> +bias, *1/sqrt(d) -> stripe zone A (k stripe dead)
    passB2(ah, ws + WS_WQ, 2 * h, lane, acc);
    {
      float bq0 = bq[32 * h + l15], bq1 = bq[32 * h + 16 + l15];
#pragma unroll
      for (int mt = 0; mt < 2; ++mt)
#pragma unroll
        for (int nt = 0; nt < 2; ++nt)
#pragma unroll
          for (int r = 0; r < 4; ++r)
            *(short*)(zA + (16 * mt + 4 * l4 + r) * ZSTR + 2 * (16 * nt + l15)) =
                (short)f2bfu((acc[mt][nt][r] + (nt ? bq1 : bq0)) * 0.17677669529663687f);
    }
    s16x8 aq0 = *(const s16x8*)(zA + l15 * ZSTR + 16 * l4);
    s16x8 aq1 = *(const s16x8*)(zA + (16 + l15) * ZSTR + 16 * l4);

    // --- QK^T
    f32x4 sc[2][2];
    sc[0][0] = MFMA16(aq0, bk0, zf);
    sc[0][1] = MFMA16(aq0, bk1, zf);
    sc[1][0] = MFMA16(aq1, bk0, zf);
    sc[1][1] = MFMA16(aq1, bk1, zf);

    // --- bias + softmax (rows in regs, 16-lane shuffle reduce), P -> zone A
    const float lamh = lam[h];
#pragma unroll
    for (int mh = 0; mh < 2; ++mh)
#pragma unroll
      for (int r = 0; r < 4; ++r) {
        float tr = trow[mh * 4 + r];
        float a0 = sc[mh][0][r] - lamh * fabsf(tr - tc0);
        float a1 = sc[mh][1][r] - lamh * fabsf(tr - tc1);
        float m = fmaxf(a0, a1);
        m = fmaxf(m, __shfl_xor(m, 1)); m = fmaxf(m, __shfl_xor(m, 2));
        m = fmaxf(m, __shfl_xor(m, 4)); m = fmaxf(m, __shfl_xor(m, 8));
        float e0 = __expf(a0 - m), e1 = __expf(a1 - m);
        float su = e0 + e1;
        su += __shfl_xor(su, 1); su += __shfl_xor(su, 2);
        su += __shfl_xor(su, 4); su += __shfl_xor(su, 8);
        float inv = 1.0f / su;
        int t = 16 * mh + 4 * l4 + r;
        *(short*)(zA + t * ZSTR + 2 * l15)        = (short)f2bfu(e0 * inv);
        *(short*)(zA + t * ZSTR + 2 * (l15 + 16)) = (short)f2bfu(e1 * inv);
      }

    // --- PV + gate -> packed regs (region A still holds h; can't write yet)
    s16x8 ap0 = *(const s16x8*)(zA + l15 * ZSTR + 16 * l4);
    s16x8 ap1 = *(const s16x8*)(zA + (16 + l15) * ZSTR + 16 * l4);
    s16x8 bv0 = *(const s16x8*)(zB + l15 * ZSTR + 16 * l4);
    s16x8 bv1 = *(const s16x8*)(zB + (16 + l15) * ZSTR + 16 * l4);
#pragma unroll
    for (int mh = 0; mh < 2; ++mh)
#pragma unroll
      for (int nd = 0; nd < 2; ++nd) {
        f32x4 oa = MFMA16(mh ? ap1 : ap0, nd ? bv1 : bv0, zf);
#pragma unroll
        for (int rp = 0; rp < 2; ++rp) {
          unsigned gu = gpk[mh][nd][rp];
          gopk[hp][mh][nd][rp] =
              pack2(oa[2 * rp] * bf_lo(gu), oa[2 * rp + 1] * bf_hi(gu));
        }
      }
  }
  __syncthreads();   // all waves done reading h -> region A becomes g*o

  // ---------------- Phase 3a: publish g*o (bf16) to region A ----------------
#pragma unroll
  for (int hp = 0; hp < 2; ++hp)
#pragma unroll
    for (int mh = 0; mh < 2; ++mh)
#pragma unroll
      for (int nd = 0; nd < 2; ++nd)
#pragma unroll
        for (int rp = 0; rp < 2; ++rp) {
          unsigned gu = gopk[hp][mh][nd][rp];
          int j = 32 * (2 * w + hp) + 16 * nd + l15;
          int r0 = 16 * mh + 4 * l4 + 2 * rp;
          *(short*)(lds + LDS_A + r0 * RS + 2 * j)       = (short)(gu & 0xFFFFu);
          *(short*)(lds + LDS_A + (r0 + 1) * RS + 2 * j) = (short)(gu >> 16);
        }
  __syncthreads();

  // ---------------- Phase 3b: out = x + (g*o) @ Wo^T  (two halves) ----------------
#pragma unroll
  for (int half = 0; half < 2; ++half) {
    f32x4 facc[2][2];
    gemmNT<2>(lds, ws + WS_WO, 4 * w + 2 * half, lane, facc);
#pragma unroll
    for (int mt = 0; mt < 2; ++mt)
#pragma unroll
      for (int nt = 0; nt < 2; ++nt)
#pragma unroll
        for (int r = 0; r < 4; ++r) {
          int row = 16 * mt + 4 * l4 + r;
          int j = 64 * w + 32 * half + 16 * nt + l15;
          size_t gi = ((size_t)blk * 32 + row) * 256 + j;
          out[gi] = facc[mt][nt][r] + x[gi];
        }
  }
}

extern "C" void kernel_launch(void* const* d_in, const int* in_sizes, int n_in,
                              void* d_out, int out_size, void* d_ws, size_t ws_size,
                              hipStream_t stream) {
  const float* x     = (const float*)d_in[0];
  const float* ts    = (const float*)d_in[1];
  const float* gamma = (const float*)d_in[3];
  const float* beta  = (const float*)d_in[4];
  const float* Wq    = (const float*)d_in[5];
  const float* bq    = (const float*)d_in[6];
  const float* Wk    = (const float*)d_in[7];
  const float* Wv    = (const float*)d_in[8];
  const float* Wg    = (const float*)d_in[9];
  const float* Wo    = (const float*)d_in[10];
  const float* ll    = (const float*)d_in[11];
  char* ws   = (char*)d_ws;
  float* out = (float*)d_out;

  prep_kernel<<<161, 256, 0, stream>>>(Wq, Wk, Wv, Wg, Wo, ll, ws);

  (void)hipFuncSetAttribute((const void*)fused_kernel,
                            hipFuncAttributeMaxDynamicSharedMemorySize, LDS_TOTAL);
  fused_kernel<<<4096, 256, LDS_TOTAL, stream>>>(x, ts, gamma, beta, bq, ws, out);
}